// Round 8
// baseline (423.248 us; speedup 1.0000x reference)
//
#include <hip/hip_runtime.h>
#include <math.h>

#define BATCH 256
#define M 128        // txt rows
#define NIMG 127     // valid img cols
#define NP 128       // padded img cols
#define D 1024
#define ITERS 50
#define ASTRIDE 132  // A-LDS row stride in floats (128 + 4)
#define NTHREADS 1024
#define NWAVES 16
#define NHALF 32     // 32 k-halves of 32 floats each (= D/32)

typedef __attribute__((ext_vector_type(8))) short bf16x8;
typedef __attribute__((ext_vector_type(4))) float floatx4;

// pack two floats to bf16x2 (RNE), bit-level
static __device__ __forceinline__ unsigned pack_bf16x2(float a, float b) {
    unsigned ua = __builtin_bit_cast(unsigned, a);
    unsigned ub = __builtin_bit_cast(unsigned, b);
    ua += 0x7fffu + ((ua >> 16) & 1u);
    ub += 0x7fffu + ((ub >> 16) & 1u);
    return (ua >> 16) | (ub & 0xffff0000u);
}

static __device__ __forceinline__ bf16x8 pack8(const float4& a, const float4& b) {
    union { unsigned u[4]; bf16x8 v; } r;
    r.u[0] = pack_bf16x2(a.x, a.y);
    r.u[1] = pack_bf16x2(a.z, a.w);
    r.u[2] = pack_bf16x2(b.x, b.y);
    r.u[3] = pack_bf16x2(b.z, b.w);
    return r.v;
}

static __device__ __forceinline__ float sq8(const float4& a, const float4& b, float s) {
    s = fmaf(a.x, a.x, s); s = fmaf(a.y, a.y, s);
    s = fmaf(a.z, a.z, s); s = fmaf(a.w, a.w, s);
    s = fmaf(b.x, b.x, s); s = fmaf(b.y, b.y, s);
    s = fmaf(b.z, b.z, s); s = fmaf(b.w, b.w, s);
    return s;
}

// DPP row_ror:n add (16-lane rotate) — VALU-pipe reduction, no DS ops
template<int CTRL>
static __device__ __forceinline__ float dpp_add(float v) {
    int s = __builtin_amdgcn_update_dpp(0, __builtin_bit_cast(int, v), CTRL, 0xf, 0xf, true);
    return v + __builtin_bit_cast(float, s);
}
static __device__ __forceinline__ float red16(float v) {
    v = dpp_add<0x121>(v);
    v = dpp_add<0x122>(v);
    v = dpp_add<0x124>(v);
    v = dpp_add<0x128>(v);
    return v;
}

// 8 float4 named fields -> stays in VGPRs (no runtime indexing)
struct HalfBuf { float4 x0a, x0b, x1a, x1b, y0a, y0b, y1a, y1b; };

static __device__ __forceinline__ void load_half(HalfBuf& hb,
                                                 const float* __restrict__ xr0,
                                                 const float* __restrict__ xr1,
                                                 const float* __restrict__ yr0,
                                                 const float* __restrict__ yr1,
                                                 int h) {
    const int o = h * 32;
    hb.x0a = *(const float4*)(xr0 + o); hb.x0b = *(const float4*)(xr0 + o + 4);
    hb.x1a = *(const float4*)(xr1 + o); hb.x1b = *(const float4*)(xr1 + o + 4);
    hb.y0a = *(const float4*)(yr0 + o); hb.y0b = *(const float4*)(yr0 + o + 4);
    hb.y1a = *(const float4*)(yr1 + o); hb.y1b = *(const float4*)(yr1 + o + 4);
}

static __device__ __forceinline__ void proc_half(const HalfBuf& hb, bool yv0, bool yv1,
                                                 bool doX, bool doY,
                                                 floatx4 (&acc)[2][2],
                                                 float& ssx0, float& ssx1,
                                                 float& ssy0, float& ssy1) {
    const float4 z = make_float4(0.f, 0.f, 0.f, 0.f);
    float4 ya0 = yv0 ? hb.y0a : z, yb0 = yv0 ? hb.y0b : z;
    float4 ya1 = yv1 ? hb.y1a : z, yb1 = yv1 ? hb.y1b : z;

    if (doX) { ssx0 = sq8(hb.x0a, hb.x0b, ssx0); ssx1 = sq8(hb.x1a, hb.x1b, ssx1); }
    if (doY) { ssy0 = sq8(ya0, yb0, ssy0);       ssy1 = sq8(ya1, yb1, ssy1); }

    // fragment mapping identical to the LDS path: lane(col,quad) holds
    // row = base+tr*16+col, k = h*32 + quad*8 .. +8 (quad*8 folded into ptr)
    bf16x8 af0 = pack8(hb.x0a, hb.x0b);
    bf16x8 af1 = pack8(hb.x1a, hb.x1b);
    bf16x8 bf0 = pack8(ya0, yb0);
    bf16x8 bf1 = pack8(ya1, yb1);

    acc[0][0] = __builtin_amdgcn_mfma_f32_16x16x32_bf16(af0, bf0, acc[0][0], 0, 0, 0);
    acc[0][1] = __builtin_amdgcn_mfma_f32_16x16x32_bf16(af0, bf1, acc[0][1], 0, 0, 0);
    acc[1][0] = __builtin_amdgcn_mfma_f32_16x16x32_bf16(af1, bf0, acc[1][0], 0, 0, 0);
    acc[1][1] = __builtin_amdgcn_mfma_f32_16x16x32_bf16(af1, bf1, acc[1][1], 0, 0, 0);
}

// ============ FUSED: LDS-free GEMM -> A (in LDS) -> 50 IPOT iters -> loss ====
// The k-loop has ZERO LDS traffic and ZERO sync barriers: each wave loads its
// MFMA fragments straight from global (row-major rows ARE the fragments),
// converts to bf16 in-register, and accumulates. 4 waves share each X/Y row
// panel -> 4x read amplification served by L2 (readers hit the same lines in
// the same phase; bare s_barriers every 8 halves bound wave drift). This
// removes the stage->barrier->ds_read chain that kept every pipe <25% busy.
__launch_bounds__(NTHREADS, 1)
__global__ void fused_kernel(const float* __restrict__ xg,
                             const float* __restrict__ yg,
                             const int* __restrict__ xnum,
                             const int* __restrict__ ynum,
                             float* __restrict__ out)
{
    __shared__ __align__(16) float Alds[M * ASTRIDE];     // 67584 B
    __shared__ __align__(16) float partCS[NWAVES * 128];  // 8192 B
    __shared__ __align__(16) float sdelta[NP];
    __shared__ __align__(16) float sxmask[M];
    __shared__ __align__(16) float symask[NP];
    __shared__ __align__(16) float sinvx[M];
    __shared__ __align__(16) float sinvy[NP];
    __shared__ float sxl_s, syl_s;
    __shared__ unsigned scnt[2 * NWAVES];
    __shared__ float swsum[NWAVES];

    const int b    = blockIdx.x;
    const int t    = threadIdx.x;
    const int lane = t & 63;
    const int w    = t >> 6;          // 0..15
    const int tj   = t & 15;
    const int i0   = (t >> 4) * 2;    // ipot row base (2 rows/thread)
    const int j0   = tj * 8;          // ipot col base

    // ---- masks + valid-lengths ----
    bool tpad = true, ipad = true;
    if (t < M)  { tpad = (xnum[b * M + t] == 0); sxmask[t] = tpad ? 1e4f : 0.0f; }
    if (t < NP) { ipad = !(t < NIMG && ynum[b * 128 + t + 1] != 0); symask[t] = ipad ? 1e4f : 0.0f; }
    unsigned long long bx = __ballot(t < M  && !tpad);
    unsigned long long by = __ballot(t < NP && !ipad);
    if (lane == 0) { scnt[w] = (unsigned)__popcll(bx); scnt[NWAVES + w] = (unsigned)__popcll(by); }
    __syncthreads();
    if (t == 0) {
        float xl = 0.f, yl = 0.f;
        for (int k = 0; k < NWAVES; ++k) { xl += scnt[k]; yl += scnt[NWAVES + k]; }
        sxl_s = xl; syl_s = yl;
    }

    // ---- GEMM phase (LDS-free) ----
    const int wm = w & 3, wn = w >> 2;        // 4x4 wave grid
    const int col = lane & 15, quad = lane >> 4;
    const int mbase = wm * 32, nbase = wn * 32;

    const float* xb = xg + (size_t)b * M * D;
    const float* yb = yg + ((size_t)b * 128 + 1) * D;

    const float* xr0 = xb + (size_t)(mbase + col) * D + quad * 8;
    const float* xr1 = xb + (size_t)(mbase + 16 + col) * D + quad * 8;
    const int yi0 = nbase + col, yi1 = nbase + 16 + col;
    const bool yv0 = (yi0 < NIMG), yv1 = (yi1 < NIMG);
    const float* yr0 = yb + (size_t)(yv0 ? yi0 : 0) * D + quad * 8;
    const float* yr1 = yb + (size_t)(yv1 ? yi1 : 0) * D + quad * 8;

    floatx4 acc[2][2];
#pragma unroll
    for (int a = 0; a < 2; ++a)
#pragma unroll
        for (int c = 0; c < 2; ++c) acc[a][c] = (floatx4)0.0f;

    float ssx0 = 0.f, ssx1 = 0.f, ssy0 = 0.f, ssy1 = 0.f;
    const bool doX = (wn == 0);   // waves 0..3 cover all 128 X rows
    const bool doY = (wm == 0);   // waves 0,4,8,12 cover all 128 Y rows

    // 2-buffer register pipeline over 32 k-halves; no barriers, no LDS
    HalfBuf A, B;
    load_half(A, xr0, xr1, yr0, yr1, 0);
    load_half(B, xr0, xr1, yr0, yr1, 1);

#pragma unroll 1
    for (int hh = 0; hh < NHALF; hh += 2) {
        proc_half(A, yv0, yv1, doX, doY, acc, ssx0, ssx1, ssy0, ssy1);
        if (hh + 2 < NHALF) load_half(A, xr0, xr1, yr0, yr1, hh + 2);
        proc_half(B, yv0, yv1, doX, doY, acc, ssx0, ssx1, ssy0, ssy1);
        if (hh + 3 < NHALF) load_half(B, xr0, xr1, yr0, yr1, hh + 3);
        // bare drift-control barrier (no waitcnt semantics needed: no LDS
        // data exchange) — keeps the 4-way-shared panels L2-resident
        if ((hh & 6) == 6) __builtin_amdgcn_s_barrier();
    }

    // ---- norms: reduce the 4 quad-partials per row via shfl butterfly ----
    if (doX) {
        float v0 = ssx0; v0 += __shfl_xor(v0, 16); v0 += __shfl_xor(v0, 32);
        float v1 = ssx1; v1 += __shfl_xor(v1, 16); v1 += __shfl_xor(v1, 32);
        if (quad == 0) {
            sinvx[mbase + col]      = 1.0f / fmaxf(sqrtf(v0), 1e-5f);
            sinvx[mbase + 16 + col] = 1.0f / fmaxf(sqrtf(v1), 1e-5f);
        }
    }
    if (doY) {
        float v0 = ssy0; v0 += __shfl_xor(v0, 16); v0 += __shfl_xor(v0, 32);
        float v1 = ssy1; v1 += __shfl_xor(v1, 16); v1 += __shfl_xor(v1, 32);
        if (quad == 0) {
            sinvy[nbase + col]      = 1.0f / fmaxf(sqrtf(v0), 1e-5f);
            sinvy[nbase + 16 + col] = 1.0f / fmaxf(sqrtf(v1), 1e-5f);
        }
    }
    __syncthreads();

    // ---- epilogue: A = exp(2*cos - 2) masked, into LDS ----
#pragma unroll
    for (int tr = 0; tr < 2; ++tr)
#pragma unroll
        for (int tc = 0; tc < 2; ++tc) {
            const int n = nbase + tc * 16 + col;
            const float ivy_n = sinvy[n];
            const float ymf   = symask[n];
#pragma unroll
            for (int reg = 0; reg < 4; ++reg) {
                const int m = mbase + tr * 16 + quad * 4 + reg;
                const float p = acc[tr][tc][reg] * sinvx[m] * ivy_n;
                const float a = (sxmask[m] + ymf > 0.0f) ? 0.0f : expf(2.0f * p - 2.0f);
                Alds[m * ASTRIDE + n] = a;
            }
        }
    __syncthreads();

    // ---- IPOT phase: 2 rows x 8 cols per thread (R7 structure) ----
    const float xl = sxl_s, yl = syl_s;

    float xm[2], ym[8];
    xm[0] = sxmask[i0]; xm[1] = sxmask[i0 + 1];
    *(float4*)ym       = *(const float4*)(&symask[j0]);
    *(float4*)(ym + 4) = *(const float4*)(&symask[j0 + 4]);

    float sn[2];
#pragma unroll
    for (int r = 0; r < 2; ++r)
        sn[r] = (xm[r] > 0.0f) ? 0.0f : __builtin_amdgcn_rcpf(xl);

    float Af[2][8], Q[2][8];
#pragma unroll
    for (int r = 0; r < 2; ++r) {
        float4 a0 = *(const float4*)(&Alds[(i0 + r) * ASTRIDE + j0]);
        float4 a1 = *(const float4*)(&Alds[(i0 + r) * ASTRIDE + j0 + 4]);
        Af[r][0] = a0.x; Af[r][1] = a0.y; Af[r][2] = a0.z; Af[r][3] = a0.w;
        Af[r][4] = a1.x; Af[r][5] = a1.y; Af[r][6] = a1.z; Af[r][7] = a1.w;
#pragma unroll
        for (int j = 0; j < 8; ++j) Q[r][j] = Af[r][j];
    }
    __syncthreads();

    float lp = 0.0f;
    for (int itn = 0; itn < ITERS; ++itn) {
        // ---- colsum[j] = sum_i sigma[i] Q[i][j] ----
        float cp[8] = {0.f,0.f,0.f,0.f,0.f,0.f,0.f,0.f};
#pragma unroll
        for (int r = 0; r < 2; ++r)
#pragma unroll
            for (int j = 0; j < 8; ++j)
                cp[j] = fmaf(sn[r], Q[r][j], cp[j]);
#pragma unroll
        for (int j = 0; j < 8; ++j) {
            cp[j] += __shfl_xor(cp[j], 16);
            cp[j] += __shfl_xor(cp[j], 32);
        }
        if (lane < 16) {
            float4 c0 = make_float4(cp[0], cp[1], cp[2], cp[3]);
            float4 c1 = make_float4(cp[4], cp[5], cp[6], cp[7]);
            *(float4*)(&partCS[w * 128 + j0])     = c0;
            *(float4*)(&partCS[w * 128 + j0 + 4]) = c1;
        }
        __syncthreads();
        if (t < NP) {
            float s = 0.f;
#pragma unroll
            for (int w8 = 0; w8 < NWAVES; ++w8) s += partCS[w8 * 128 + t];
            sdelta[t] = __builtin_amdgcn_rcpf(yl * s + symask[t]);
        }
        __syncthreads();
        // ---- rowsum[i] = sum_j delta[j] Q[i][j] ----
        float dl[8];
        *(float4*)dl       = *(const float4*)(&sdelta[j0]);
        *(float4*)(dl + 4) = *(const float4*)(&sdelta[j0 + 4]);
        float rp[2] = {0.f, 0.f};
#pragma unroll
        for (int r = 0; r < 2; ++r)
#pragma unroll
            for (int j = 0; j < 8; ++j)
                rp[r] = fmaf(dl[j], Q[r][j], rp[r]);
#pragma unroll
        for (int r = 0; r < 2; ++r) rp[r] = red16(rp[r]);
#pragma unroll
        for (int r = 0; r < 2; ++r) rp[r] = __shfl(rp[r], lane & 48);
#pragma unroll
        for (int r = 0; r < 2; ++r)
            sn[r] = __builtin_amdgcn_rcpf(xl * rp[r] + xm[r]);

        if (itn < ITERS - 1) {
#pragma unroll
            for (int r = 0; r < 2; ++r) {
                const float f = sn[r];
#pragma unroll
                for (int j = 0; j < 8; ++j)
                    Q[r][j] *= Af[r][j] * dl[j] * f;
            }
        } else {
#pragma unroll
            for (int r = 0; r < 2; ++r)
#pragma unroll
                for (int j = 0; j < 8; ++j) {
                    const float a = Af[r][j];
                    if (a > 0.0f)
                        lp = fmaf(-0.5f * logf(a) * dl[j] * sn[r], Q[r][j], lp);
                }
        }
    }

#pragma unroll
    for (int off = 32; off > 0; off >>= 1) lp += __shfl_down(lp, off);
    if (lane == 0) swsum[w] = lp;
    __syncthreads();
    if (t == 0) {
        float tot = 0.f;
        for (int k = 0; k < NWAVES; ++k) tot += swsum[k];
        atomicAdd(out, 0.01f * tot);
    }
}

extern "C" void kernel_launch(void* const* d_in, const int* in_sizes, int n_in,
                              void* d_out, int out_size, void* d_ws, size_t ws_size,
                              hipStream_t stream) {
    const float* x  = (const float*)d_in[0];
    const float* y  = (const float*)d_in[1];
    const int*   xn = (const int*)d_in[2];
    const int*   yn = (const int*)d_in[3];
    float* out = (float*)d_out;
    (void)d_ws; (void)ws_size;

    (void)hipMemsetAsync(out, 0, (size_t)out_size * sizeof(float), stream);
    fused_kernel<<<dim3(BATCH), dim3(NTHREADS), 0, stream>>>(x, y, xn, yn, out);
}

// Round 9
// 353.936 us; speedup vs baseline: 1.1958x; 1.1958x over previous
//
#include <hip/hip_runtime.h>
#include <math.h>

#define BATCH 256
#define M 128        // txt rows
#define NIMG 127     // valid img cols
#define NP 128       // padded img cols
#define D 1024
#define ITERS 50
#define ASTRIDE 132  // A-LDS row stride in floats (128 + 4)
#define NTHREADS 512
#define NWAVES 8
#define NHALF 32     // 32 k-halves of 32 floats each (= D/32)

typedef __attribute__((ext_vector_type(8))) short bf16x8;
typedef __attribute__((ext_vector_type(4))) float floatx4;

// pack two floats to bf16x2 (RNE), bit-level
static __device__ __forceinline__ unsigned pack_bf16x2(float a, float b) {
    unsigned ua = __builtin_bit_cast(unsigned, a);
    unsigned ub = __builtin_bit_cast(unsigned, b);
    ua += 0x7fffu + ((ua >> 16) & 1u);
    ub += 0x7fffu + ((ub >> 16) & 1u);
    return (ua >> 16) | (ub & 0xffff0000u);
}

static __device__ __forceinline__ bf16x8 pack8(const float4& a, const float4& b) {
    union { unsigned u[4]; bf16x8 v; } r;
    r.u[0] = pack_bf16x2(a.x, a.y);
    r.u[1] = pack_bf16x2(a.z, a.w);
    r.u[2] = pack_bf16x2(b.x, b.y);
    r.u[3] = pack_bf16x2(b.z, b.w);
    return r.v;
}

static __device__ __forceinline__ float sq8(const float4& a, const float4& b, float s) {
    s = fmaf(a.x, a.x, s); s = fmaf(a.y, a.y, s);
    s = fmaf(a.z, a.z, s); s = fmaf(a.w, a.w, s);
    s = fmaf(b.x, b.x, s); s = fmaf(b.y, b.y, s);
    s = fmaf(b.z, b.z, s); s = fmaf(b.w, b.w, s);
    return s;
}

// DPP row_ror:n add (16-lane rotate) — VALU-pipe reduction, no DS ops
template<int CTRL>
static __device__ __forceinline__ float dpp_add(float v) {
    int s = __builtin_amdgcn_update_dpp(0, __builtin_bit_cast(int, v), CTRL, 0xf, 0xf, true);
    return v + __builtin_bit_cast(float, s);
}
static __device__ __forceinline__ float red16(float v) {
    v = dpp_add<0x121>(v);
    v = dpp_add<0x122>(v);
    v = dpp_add<0x124>(v);
    v = dpp_add<0x128>(v);
    return v;
}

// 12 named float4 fields -> stays in VGPRs (no runtime indexing)
struct HalfBuf {
    float4 x0a, x0b, x1a, x1b;
    float4 y0a, y0b, y1a, y1b, y2a, y2b, y3a, y3b;
};

static __device__ __forceinline__ void load_half(HalfBuf& hb,
                                                 const float* __restrict__ xr0,
                                                 const float* __restrict__ xr1,
                                                 const float* __restrict__ yr0,
                                                 const float* __restrict__ yr1,
                                                 const float* __restrict__ yr2,
                                                 const float* __restrict__ yr3,
                                                 int h) {
    const int o = h * 32;
    hb.x0a = *(const float4*)(xr0 + o); hb.x0b = *(const float4*)(xr0 + o + 4);
    hb.x1a = *(const float4*)(xr1 + o); hb.x1b = *(const float4*)(xr1 + o + 4);
    hb.y0a = *(const float4*)(yr0 + o); hb.y0b = *(const float4*)(yr0 + o + 4);
    hb.y1a = *(const float4*)(yr1 + o); hb.y1b = *(const float4*)(yr1 + o + 4);
    hb.y2a = *(const float4*)(yr2 + o); hb.y2b = *(const float4*)(yr2 + o + 4);
    hb.y3a = *(const float4*)(yr3 + o); hb.y3b = *(const float4*)(yr3 + o + 4);
}

static __device__ __forceinline__ void proc_half(const HalfBuf& hb,
                                                 bool yv0, bool yv1, bool yv2, bool yv3,
                                                 bool doX, bool doY,
                                                 floatx4 (&acc)[2][4],
                                                 float& ssx0, float& ssx1,
                                                 float (&ssy)[4]) {
    const float4 z = make_float4(0.f, 0.f, 0.f, 0.f);
    float4 y0a = yv0 ? hb.y0a : z, y0b = yv0 ? hb.y0b : z;
    float4 y1a = yv1 ? hb.y1a : z, y1b = yv1 ? hb.y1b : z;
    float4 y2a = yv2 ? hb.y2a : z, y2b = yv2 ? hb.y2b : z;
    float4 y3a = yv3 ? hb.y3a : z, y3b = yv3 ? hb.y3b : z;

    if (doX) { ssx0 = sq8(hb.x0a, hb.x0b, ssx0); ssx1 = sq8(hb.x1a, hb.x1b, ssx1); }
    if (doY) {
        ssy[0] = sq8(y0a, y0b, ssy[0]);
        ssy[1] = sq8(y1a, y1b, ssy[1]);
        ssy[2] = sq8(y2a, y2b, ssy[2]);
        ssy[3] = sq8(y3a, y3b, ssy[3]);
    }

    // fragment mapping identical to the verified LDS path: lane(col,quad)
    // holds row = base+idx*16+col, k = h*32 + quad*8 .. +8 (quad*8 in ptr)
    bf16x8 af0 = pack8(hb.x0a, hb.x0b);
    bf16x8 af1 = pack8(hb.x1a, hb.x1b);
    bf16x8 bf0 = pack8(y0a, y0b);
    bf16x8 bf1 = pack8(y1a, y1b);
    bf16x8 bf2 = pack8(y2a, y2b);
    bf16x8 bf3 = pack8(y3a, y3b);

    acc[0][0] = __builtin_amdgcn_mfma_f32_16x16x32_bf16(af0, bf0, acc[0][0], 0, 0, 0);
    acc[0][1] = __builtin_amdgcn_mfma_f32_16x16x32_bf16(af0, bf1, acc[0][1], 0, 0, 0);
    acc[0][2] = __builtin_amdgcn_mfma_f32_16x16x32_bf16(af0, bf2, acc[0][2], 0, 0, 0);
    acc[0][3] = __builtin_amdgcn_mfma_f32_16x16x32_bf16(af0, bf3, acc[0][3], 0, 0, 0);
    acc[1][0] = __builtin_amdgcn_mfma_f32_16x16x32_bf16(af1, bf0, acc[1][0], 0, 0, 0);
    acc[1][1] = __builtin_amdgcn_mfma_f32_16x16x32_bf16(af1, bf1, acc[1][1], 0, 0, 0);
    acc[1][2] = __builtin_amdgcn_mfma_f32_16x16x32_bf16(af1, bf2, acc[1][2], 0, 0, 0);
    acc[1][3] = __builtin_amdgcn_mfma_f32_16x16x32_bf16(af1, bf3, acc[1][3], 0, 0, 0);
}

// ============ FUSED: LDS-free GEMM -> A (in LDS) -> 50 IPOT iters -> loss ====
// R8 validated the mechanism (FETCH stayed at compulsory: L2 absorbs the
// panel sharing) but died on spill: 1024-thread blocks get a 64-VGPR budget
// on this toolchain (R7+R8). 512 threads + __launch_bounds__(512,1) is the
// proven register-safe config (R4/R6: 108 VGPRs allocated, no spill; cap 256
// at 2 waves/SIMD). 8 waves in a 4(m)x2(n) grid, 32x64 tile each, acc[2][4];
// per lane 2 X-rows + 4 Y-rows, double-buffered -> ~96 buffer VGPRs in flight.
__launch_bounds__(NTHREADS, 1)
__global__ void fused_kernel(const float* __restrict__ xg,
                             const float* __restrict__ yg,
                             const int* __restrict__ xnum,
                             const int* __restrict__ ynum,
                             float* __restrict__ out)
{
    __shared__ __align__(16) float Alds[M * ASTRIDE];     // 67584 B
    __shared__ __align__(16) float partCS[NWAVES * 128];  // 4096 B
    __shared__ __align__(16) float sdelta[NP];
    __shared__ __align__(16) float sxmask[M];
    __shared__ __align__(16) float symask[NP];
    __shared__ __align__(16) float sinvx[M];
    __shared__ __align__(16) float sinvy[NP];
    __shared__ float sxl_s, syl_s;
    __shared__ unsigned scnt[2 * NWAVES];
    __shared__ float swsum[NWAVES];

    const int b    = blockIdx.x;
    const int t    = threadIdx.x;
    const int lane = t & 63;
    const int w    = t >> 6;          // 0..7
    const int tj   = t & 15;
    const int i0   = (t >> 4) * 4;    // ipot row base (4 rows/thread)
    const int j0   = tj * 8;          // ipot col base

    // ---- masks + valid-lengths ----
    bool tpad = true, ipad = true;
    if (t < M)  { tpad = (xnum[b * M + t] == 0); sxmask[t] = tpad ? 1e4f : 0.0f; }
    if (t < NP) { ipad = !(t < NIMG && ynum[b * 128 + t + 1] != 0); symask[t] = ipad ? 1e4f : 0.0f; }
    unsigned long long bx = __ballot(t < M  && !tpad);
    unsigned long long by = __ballot(t < NP && !ipad);
    if (lane == 0) { scnt[w] = (unsigned)__popcll(bx); scnt[NWAVES + w] = (unsigned)__popcll(by); }
    __syncthreads();
    if (t == 0) {
        float xl = 0.f, yl = 0.f;
        for (int k = 0; k < NWAVES; ++k) { xl += scnt[k]; yl += scnt[NWAVES + k]; }
        sxl_s = xl; syl_s = yl;
    }

    // ---- GEMM phase (LDS-free, no barriers in the k-loop) ----
    const int wm = w & 3, wn = w >> 2;        // 4x2 wave grid
    const int col = lane & 15, quad = lane >> 4;
    const int mbase = wm * 32, nbase = wn * 64;

    const float* xb = xg + (size_t)b * M * D;
    const float* yb = yg + ((size_t)b * 128 + 1) * D;

    const float* xr0 = xb + (size_t)(mbase + col) * D + quad * 8;
    const float* xr1 = xb + (size_t)(mbase + 16 + col) * D + quad * 8;
    const int yi0 = nbase + col,      yi1 = nbase + 16 + col;
    const int yi2 = nbase + 32 + col, yi3 = nbase + 48 + col;
    const bool yv0 = (yi0 < NIMG), yv1 = (yi1 < NIMG);
    const bool yv2 = (yi2 < NIMG), yv3 = (yi3 < NIMG);
    const float* yr0 = yb + (size_t)(yv0 ? yi0 : 0) * D + quad * 8;
    const float* yr1 = yb + (size_t)(yv1 ? yi1 : 0) * D + quad * 8;
    const float* yr2 = yb + (size_t)(yv2 ? yi2 : 0) * D + quad * 8;
    const float* yr3 = yb + (size_t)(yv3 ? yi3 : 0) * D + quad * 8;

    floatx4 acc[2][4];
#pragma unroll
    for (int a = 0; a < 2; ++a)
#pragma unroll
        for (int c = 0; c < 4; ++c) acc[a][c] = (floatx4)0.0f;

    float ssx0 = 0.f, ssx1 = 0.f;
    float ssy[4] = {0.f, 0.f, 0.f, 0.f};
    const bool doX = (wn == 0);   // waves 0..3 cover all 128 X rows
    const bool doY = (wm == 0);   // waves 0,4 cover all 128 Y rows

    // 2-buffer register pipeline over 32 k-halves
    HalfBuf A, B;
    load_half(A, xr0, xr1, yr0, yr1, yr2, yr3, 0);
    load_half(B, xr0, xr1, yr0, yr1, yr2, yr3, 1);

#pragma unroll 1
    for (int hh = 0; hh < NHALF; hh += 2) {
        proc_half(A, yv0, yv1, yv2, yv3, doX, doY, acc, ssx0, ssx1, ssy);
        if (hh + 2 < NHALF) load_half(A, xr0, xr1, yr0, yr1, yr2, yr3, hh + 2);
        proc_half(B, yv0, yv1, yv2, yv3, doX, doY, acc, ssx0, ssx1, ssy);
        if (hh + 3 < NHALF) load_half(B, xr0, xr1, yr0, yr1, yr2, yr3, hh + 3);
        // bare drift-control barrier — keeps the 2x/4x-shared panels L2-hot
        if ((hh & 6) == 6) __builtin_amdgcn_s_barrier();
    }

    // ---- norms: reduce the 4 quad-partials per row via shfl butterfly ----
    if (doX) {
        float v0 = ssx0; v0 += __shfl_xor(v0, 16); v0 += __shfl_xor(v0, 32);
        float v1 = ssx1; v1 += __shfl_xor(v1, 16); v1 += __shfl_xor(v1, 32);
        if (quad == 0) {
            sinvx[mbase + col]      = 1.0f / fmaxf(sqrtf(v0), 1e-5f);
            sinvx[mbase + 16 + col] = 1.0f / fmaxf(sqrtf(v1), 1e-5f);
        }
    }
    if (doY) {
#pragma unroll
        for (int tc = 0; tc < 4; ++tc) {
            float v = ssy[tc]; v += __shfl_xor(v, 16); v += __shfl_xor(v, 32);
            if (quad == 0)
                sinvy[nbase + tc * 16 + col] = 1.0f / fmaxf(sqrtf(v), 1e-5f);
        }
    }
    __syncthreads();

    // ---- epilogue: A = exp(2*cos - 2) masked, into LDS ----
#pragma unroll
    for (int tr = 0; tr < 2; ++tr)
#pragma unroll
        for (int tc = 0; tc < 4; ++tc) {
            const int n = nbase + tc * 16 + col;
            const float ivy_n = sinvy[n];
            const float ymf   = symask[n];
#pragma unroll
            for (int reg = 0; reg < 4; ++reg) {
                const int m = mbase + tr * 16 + quad * 4 + reg;
                const float p = acc[tr][tc][reg] * sinvx[m] * ivy_n;
                const float a = (sxmask[m] + ymf > 0.0f) ? 0.0f : expf(2.0f * p - 2.0f);
                Alds[m * ASTRIDE + n] = a;
            }
        }
    __syncthreads();

    // ---- IPOT phase (R6 512-thread structure: 4 rows x 8 cols per thread) --
    const float xl = sxl_s, yl = syl_s;

    float xm[4], ym[8];
    *(float4*)xm       = *(const float4*)(&sxmask[i0]);
    *(float4*)ym       = *(const float4*)(&symask[j0]);
    *(float4*)(ym + 4) = *(const float4*)(&symask[j0 + 4]);

    float sn[4];
#pragma unroll
    for (int r = 0; r < 4; ++r)
        sn[r] = (xm[r] > 0.0f) ? 0.0f : __builtin_amdgcn_rcpf(xl);

    float Af[4][8], Q[4][8];
#pragma unroll
    for (int r = 0; r < 4; ++r) {
        float4 a0 = *(const float4*)(&Alds[(i0 + r) * ASTRIDE + j0]);
        float4 a1 = *(const float4*)(&Alds[(i0 + r) * ASTRIDE + j0 + 4]);
        Af[r][0] = a0.x; Af[r][1] = a0.y; Af[r][2] = a0.z; Af[r][3] = a0.w;
        Af[r][4] = a1.x; Af[r][5] = a1.y; Af[r][6] = a1.z; Af[r][7] = a1.w;
#pragma unroll
        for (int j = 0; j < 8; ++j) Q[r][j] = Af[r][j];
    }
    __syncthreads();

    float lp = 0.0f;
    for (int itn = 0; itn < ITERS; ++itn) {
        // ---- colsum[j] = sum_i sigma[i] Q[i][j] ----
        float cp[8] = {0.f,0.f,0.f,0.f,0.f,0.f,0.f,0.f};
#pragma unroll
        for (int r = 0; r < 4; ++r)
#pragma unroll
            for (int j = 0; j < 8; ++j)
                cp[j] = fmaf(sn[r], Q[r][j], cp[j]);
#pragma unroll
        for (int j = 0; j < 8; ++j) {
            cp[j] += __shfl_xor(cp[j], 16);
            cp[j] += __shfl_xor(cp[j], 32);
        }
        if (lane < 16) {
            float4 c0 = make_float4(cp[0], cp[1], cp[2], cp[3]);
            float4 c1 = make_float4(cp[4], cp[5], cp[6], cp[7]);
            *(float4*)(&partCS[w * 128 + j0])     = c0;
            *(float4*)(&partCS[w * 128 + j0 + 4]) = c1;
        }
        __syncthreads();
        if (t < NP) {
            float s = 0.f;
#pragma unroll
            for (int w8 = 0; w8 < NWAVES; ++w8) s += partCS[w8 * 128 + t];
            sdelta[t] = __builtin_amdgcn_rcpf(yl * s + symask[t]);
        }
        __syncthreads();
        // ---- rowsum[i] = sum_j delta[j] Q[i][j] ----
        float dl[8];
        *(float4*)dl       = *(const float4*)(&sdelta[j0]);
        *(float4*)(dl + 4) = *(const float4*)(&sdelta[j0 + 4]);
        float rp[4] = {0.f, 0.f, 0.f, 0.f};
#pragma unroll
        for (int r = 0; r < 4; ++r)
#pragma unroll
            for (int j = 0; j < 8; ++j)
                rp[r] = fmaf(dl[j], Q[r][j], rp[r]);
        // 16-lane DPP reduce, then broadcast the group leader's value so all
        // 16 lanes use bit-identical sigma
#pragma unroll
        for (int r = 0; r < 4; ++r) rp[r] = red16(rp[r]);
#pragma unroll
        for (int r = 0; r < 4; ++r) rp[r] = __shfl(rp[r], lane & 48);
#pragma unroll
        for (int r = 0; r < 4; ++r)
            sn[r] = __builtin_amdgcn_rcpf(xl * rp[r] + xm[r]);

        if (itn < ITERS - 1) {
#pragma unroll
            for (int r = 0; r < 4; ++r) {
                const float f = sn[r];
#pragma unroll
                for (int j = 0; j < 8; ++j)
                    Q[r][j] *= Af[r][j] * dl[j] * f;
            }
        } else {
#pragma unroll
            for (int r = 0; r < 4; ++r)
#pragma unroll
                for (int j = 0; j < 8; ++j) {
                    const float a = Af[r][j];
                    if (a > 0.0f)
                        lp = fmaf(-0.5f * logf(a) * dl[j] * sn[r], Q[r][j], lp);
                }
        }
    }

#pragma unroll
    for (int off = 32; off > 0; off >>= 1) lp += __shfl_down(lp, off);
    if (lane == 0) swsum[w] = lp;
    __syncthreads();
    if (t == 0) {
        float tot = 0.f;
        for (int k = 0; k < NWAVES; ++k) tot += swsum[k];
        atomicAdd(out, 0.01f * tot);
    }
}

extern "C" void kernel_launch(void* const* d_in, const int* in_sizes, int n_in,
                              void* d_out, int out_size, void* d_ws, size_t ws_size,
                              hipStream_t stream) {
    const float* x  = (const float*)d_in[0];
    const float* y  = (const float*)d_in[1];
    const int*   xn = (const int*)d_in[2];
    const int*   yn = (const int*)d_in[3];
    float* out = (float*)d_out;
    (void)d_ws; (void)ws_size;

    (void)hipMemsetAsync(out, 0, (size_t)out_size * sizeof(float), stream);
    fused_kernel<<<dim3(BATCH), dim3(NTHREADS), 0, stream>>>(x, y, xn, yn, out);
}